// Round 3
// baseline (298153.931 us; speedup 1.0000x reference)
//
#include <hip/hip_runtime.h>
#include <math.h>

// LSTM T=32768, B=1, I=128, H=512. Persistent kernel: 32 WGs x 512 threads.
// R3 protocol: NO cache-maintenance fences in the loop. h exchanged via
// relaxed agent-scope (coherent, per-access) atomics; per-WG flag array
// instead of one RMW counter; wave0 polls flags with one coalesced load.
// Weights re-read per step from warm L2 (fences no longer invalidate it).

#define T_SEQ 32768
#define HID   512
#define INP   128
#define NWG   32
#define NTH   512
#define HSL   16    // h elements per WG
#define KW    64    // W_hh weights per thread
#define KX    16    // W_ih weights per thread

typedef unsigned long long u64;

__device__ __forceinline__ float fast_sigmoid(float x) {
    return 1.0f / (1.0f + __expf(-x));
}
__device__ __forceinline__ float fast_tanh(float x) {
    float a = fabsf(x);
    float e = __expf(-2.0f * a);          // underflows to 0 for large a -> r=1
    float r = (1.0f - e) / (1.0f + e);
    return copysignf(r, x);
}

__global__ void __launch_bounds__(NTH, 2) lstm_persist(
    const float* __restrict__ x,
    const float* __restrict__ W_ih,
    const float* __restrict__ W_hh,
    const float* __restrict__ b_ih,
    const float* __restrict__ b_hh,
    const float* __restrict__ W1,
    const float* __restrict__ Wout,
    unsigned int* __restrict__ flags,   // 2 x 32, pre-zeroed
    float* __restrict__ hbuf,           // 2 x 512 floats, ping-pong, pre-zeroed
    float* __restrict__ out)            // pre-initialized to b_eff
{
    const int w   = blockIdx.x;
    const int tid = threadIdx.x;
    const int rl  = tid >> 3;        // 0..63 local gate row
    const int j   = tid & 7;         // K-chunk
    const int gblk   = rl >> 4;      // 0..3 (i,f,g,o)
    const int within = rl & 15;
    const int grow   = gblk * HID + w * HSL + within;

    __shared__ float gate_lds[64];

    const float4* wih4 = (const float4*)(W_ih + grow * INP + j * KX);
    const float4* whh4 = (const float4*)(W_hh + grow * HID + j * KW);
    const float brow = b_ih[grow] + b_hh[grow];

    // fused output projection vector: w_eff[col] = sum_p Wout[p] * W1[p][col]
    float weff = 0.0f;
    if (tid < HSL) {
        const int col = w * HSL + tid;
        for (int p = 0; p < 25; ++p) weff += Wout[p] * W1[p * HID + col];
    }

    float c = 0.0f;

    // prefetch x_0 chunk
    float xa[KX];
#pragma unroll
    for (int k = 0; k < KX; ++k) xa[k] = x[j * KX + k];

    for (unsigned int t = 0; t < T_SEQ; ++t) {
        // ---- wait: wave 0 polls the 32 per-WG flags (coalesced, relaxed) ----
        if (tid < 64) {
            const unsigned int* f = flags + (t & 1) * NWG;
            const int lane = tid & 31;
            while (true) {
                unsigned int v = __hip_atomic_load(&f[lane], __ATOMIC_RELAXED,
                                                   __HIP_MEMORY_SCOPE_AGENT);
                if (__ballot(v >= t) == ~0ull) break;
            }
        }
        __syncthreads();   // execution + code-motion barrier; h loads below
                           // cannot issue before wave0 observed all flags

        float a0 = 0.0f, a1 = 0.0f, a2 = 0.0f, a3 = 0.0f;

        // x contribution (x_t already in registers)
#pragma unroll
        for (int k = 0; k < KX; k += 4) {
            a0 += wih4[k >> 2].x * xa[k + 0];
            a1 += wih4[k >> 2].y * xa[k + 1];
            a2 += wih4[k >> 2].z * xa[k + 2];
            a3 += wih4[k >> 2].w * xa[k + 3];
        }

        // h gather: relaxed agent-scope (coherent) 8B loads — no cache inv
        const u64* hb2 = (const u64*)(hbuf + (t & 1) * HID) + j * (KW / 2);
#pragma unroll
        for (int k = 0; k < KW / 4; ++k) {
            const float4 wv = whh4[k];
            u64 r0 = __hip_atomic_load(&hb2[2 * k + 0], __ATOMIC_RELAXED,
                                       __HIP_MEMORY_SCOPE_AGENT);
            u64 r1 = __hip_atomic_load(&hb2[2 * k + 1], __ATOMIC_RELAXED,
                                       __HIP_MEMORY_SCOPE_AGENT);
            const float2 h0 = __builtin_bit_cast(float2, r0);
            const float2 h1 = __builtin_bit_cast(float2, r1);
            a0 += wv.x * h0.x;
            a1 += wv.y * h0.y;
            a2 += wv.z * h1.x;
            a3 += wv.w * h1.y;
        }

        // prefetch x_{t+1} (off critical path, warm L1/L2)
        const int tn = (t + 1 < T_SEQ) ? (t + 1) : t;
#pragma unroll
        for (int k = 0; k < KX; k += 4) {
            const float4 x4 = *(const float4*)&x[tn * INP + j * KX + k];
            xa[k + 0] = x4.x; xa[k + 1] = x4.y;
            xa[k + 2] = x4.z; xa[k + 3] = x4.w;
        }

        float acc = (a0 + a1) + (a2 + a3);
        acc += __shfl_xor(acc, 1);
        acc += __shfl_xor(acc, 2);
        acc += __shfl_xor(acc, 4);
        if (j == 0) gate_lds[rl] = acc + brow;
        __syncthreads();

        float hv = 0.0f;
        if (tid < HSL) {
            const float ig = gate_lds[tid];
            const float fg = gate_lds[16 + tid];
            const float gg = gate_lds[32 + tid];
            const float og = gate_lds[48 + tid];
            const float iv = fast_sigmoid(ig);
            const float fv = fast_sigmoid(fg);
            const float gv = fast_tanh(gg);
            const float ov = fast_sigmoid(og);
            c = fv * c + iv * gv;
            hv = ov * fast_tanh(c);
            // publish h (relaxed agent store: write-through, no cache flush)
            __hip_atomic_store(&hbuf[((t + 1) & 1) * HID + w * HSL + tid], hv,
                               __ATOMIC_RELAXED, __HIP_MEMORY_SCOPE_AGENT);
        }
        // drain wave0's h stores, then set this WG's flag (store, not RMW)
        if (tid < 64)
            asm volatile("s_waitcnt vmcnt(0)" ::: "memory");
        if (tid == 0)
            __hip_atomic_store(&flags[((t + 1) & 1) * NWG + w], t + 1,
                               __ATOMIC_RELAXED, __HIP_MEMORY_SCOPE_AGENT);
        // fused output projection partial — after arrival, off critical path
        if (tid < HSL) {
            float pd = hv * weff;
            pd += __shfl_xor(pd, 1);
            pd += __shfl_xor(pd, 2);
            pd += __shfl_xor(pd, 4);
            pd += __shfl_xor(pd, 8);
            if (tid == 0) atomicAdd(&out[t], pd);
        }
    }
}

// out[t] starts at b_eff = dot(b1, Wout); persistent kernel atomicAdds the
// h-projection partials on top.
__global__ void init_out(const float* __restrict__ b1,
                         const float* __restrict__ Wout,
                         float* __restrict__ out)
{
    const int t = blockIdx.x * blockDim.x + threadIdx.x;
    float be = 0.0f;
    for (int p = 0; p < 25; ++p) be += b1[p] * Wout[p];
    if (t < T_SEQ) out[t] = be;
}

extern "C" void kernel_launch(void* const* d_in, const int* in_sizes, int n_in,
                              void* d_out, int out_size, void* d_ws, size_t ws_size,
                              hipStream_t stream)
{
    const float* x    = (const float*)d_in[0];
    const float* W_ih = (const float*)d_in[1];
    const float* W_hh = (const float*)d_in[2];
    const float* b_ih = (const float*)d_in[3];
    const float* b_hh = (const float*)d_in[4];
    const float* W1   = (const float*)d_in[5];
    const float* b1   = (const float*)d_in[6];
    const float* Wout = (const float*)d_in[7];
    float* out = (float*)d_out;

    unsigned int* flags = (unsigned int*)d_ws;                 // 2*32 u32
    float*        hbuf  = (float*)((char*)d_ws + 256);         // 2*512 f32

    // zero flags + both h buffers (ws is re-poisoned before each call)
    hipMemsetAsync(d_ws, 0, 256 + 2 * HID * sizeof(float), stream);
    init_out<<<(T_SEQ + 255) / 256, 256, 0, stream>>>(b1, Wout, out);
    lstm_persist<<<NWG, NTH, 0, stream>>>(x, W_ih, W_hh, b_ih, b_hh, W1, Wout,
                                          flags, hbuf, out);
}

// Round 4
// 68226.868 us; speedup vs baseline: 4.3700x; 4.3700x over previous
//
#include <hip/hip_runtime.h>
#include <math.h>

// LSTM T=32768, B=1, I=128, H=512. Persistent kernel: 32 WGs x 512 threads.
// R4 protocol: tag-in-band h exchange. Each h element is an 8B packet
// (hi32=tag, lo32=f32 h) stored with one relaxed agent-scope atomic store.
// Consumers poll the packets directly (wave0 only, per-lane early-out) —
// no fences, no flags, no cache maintenance anywhere in the loop.
// Weights pinned in VGPRs via asm; h broadcast via LDS with bank-rotated
// read schedule (weights pre-rotated to match).

#define T_SEQ 32768
#define HID   512
#define INP   128
#define NWG   32
#define NTH   512
#define HSL   16    // h elements per WG
#define KW    64    // W_hh weights per thread
#define KX    16    // W_ih weights per thread

typedef unsigned long long u64;

__device__ __forceinline__ float fast_sigmoid(float x) {
    return 1.0f / (1.0f + __expf(-x));
}
__device__ __forceinline__ float fast_tanh(float x) {
    float a = fabsf(x);
    float e = __expf(-2.0f * a);          // underflows to 0 for large a -> r=1
    float r = (1.0f - e) / (1.0f + e);
    return copysignf(r, x);
}

__global__ void __launch_bounds__(NTH, 2) lstm_persist(
    const float* __restrict__ x,
    const float* __restrict__ W_ih,
    const float* __restrict__ W_hh,
    const float* __restrict__ b_ih,
    const float* __restrict__ b_hh,
    const float* __restrict__ W1,
    const float* __restrict__ Wout,
    u64* __restrict__ hbuf,             // 2 x 512 packets, pre-zeroed (tag 0, h 0)
    float* __restrict__ out)            // pre-initialized to b_eff
{
    const int w   = blockIdx.x;
    const int tid = threadIdx.x;
    const int rl  = tid >> 3;        // 0..63 local gate row
    const int j   = tid & 7;         // K-chunk
    const int grow = (rl >> 4) * HID + w * HSL + (rl & 15);

    __shared__ float h_lds[HID];
    __shared__ float gate_lds[64];

    // ---- W_hh row chunk, loaded in the j-rotated order the LDS reads use ----
    float wr[KW];
#pragma unroll
    for (int kk = 0; kk < 16; ++kk) {
        const int p = (kk + 2 * j) & 15;
        const float4 wv = *(const float4*)&W_hh[grow * HID + j * KW + 4 * p];
        wr[4 * kk + 0] = wv.x; wr[4 * kk + 1] = wv.y;
        wr[4 * kk + 2] = wv.z; wr[4 * kk + 3] = wv.w;
    }
    float wi[KX];
#pragma unroll
    for (int k = 0; k < KX; k += 4) {
        const float4 wv = *(const float4*)&W_ih[grow * INP + j * KX + k];
        wi[k] = wv.x; wi[k + 1] = wv.y; wi[k + 2] = wv.z; wi[k + 3] = wv.w;
    }
    float brow = b_ih[grow] + b_hh[grow];
    float weff = 0.0f;
    if (tid < HSL) {
        const int col = w * HSL + tid;
        for (int p = 0; p < 25; ++p) weff += Wout[p] * W1[p * HID + col];
    }
    // pin weights in VGPRs — opaque to in-loop memory clobbers
#pragma unroll
    for (int k = 0; k < KW; ++k) asm volatile("" : "+v"(wr[k]));
#pragma unroll
    for (int k = 0; k < KX; ++k) asm volatile("" : "+v"(wi[k]));
    asm volatile("" : "+v"(brow));
    asm volatile("" : "+v"(weff));

    float c = 0.0f;
    float xa[KX];
#pragma unroll
    for (int k = 0; k < KX; ++k) xa[k] = x[j * KX + k];

    for (unsigned int t = 0; t < T_SEQ; ++t) {
        // ---- wave0: poll the 512 tagged packets of parity buffer t&1 ----
        if (tid < 64) {
            const u64* P = hbuf + (t & 1) * HID;
            u64 pr[8];
            bool ok = false;
            do {
                if (!ok) {
                    ok = true;
#pragma unroll
                    for (int i = 0; i < 8; ++i) {
                        pr[i] = __hip_atomic_load(&P[tid + 64 * i],
                                                  __ATOMIC_RELAXED,
                                                  __HIP_MEMORY_SCOPE_AGENT);
                        ok = ok && ((unsigned int)(pr[i] >> 32) == t);
                    }
                }
            } while (__ballot(ok) != ~0ull);
            // broadcast h to LDS (stride-64: 2-way bank aliasing = free)
#pragma unroll
            for (int i = 0; i < 8; ++i)
                h_lds[tid + 64 * i] = __uint_as_float((unsigned int)pr[i]);
        }
        __syncthreads();

        float a0 = 0.0f, a1 = 0.0f, a2 = 0.0f, a3 = 0.0f;
#pragma unroll
        for (int k = 0; k < KX; k += 4) {
            a0 += wi[k + 0] * xa[k + 0];
            a1 += wi[k + 1] * xa[k + 1];
            a2 += wi[k + 2] * xa[k + 2];
            a3 += wi[k + 3] * xa[k + 3];
        }
        // h dot from LDS, j-rotated so the 8 j-streams hit disjoint bank groups
        const float4* hl4 = (const float4*)&h_lds[j * KW];
#pragma unroll
        for (int kk = 0; kk < 16; ++kk) {
            const int p = (kk + 2 * j) & 15;
            const float4 h4 = hl4[p];
            a0 += wr[4 * kk + 0] * h4.x;
            a1 += wr[4 * kk + 1] * h4.y;
            a2 += wr[4 * kk + 2] * h4.z;
            a3 += wr[4 * kk + 3] * h4.w;
        }
        // prefetch x_{t+1} (off critical path, L1/L2 stay warm — no fences)
        const int tn = (t + 1 < T_SEQ) ? (int)(t + 1) : (int)t;
#pragma unroll
        for (int k = 0; k < KX; k += 4) {
            const float4 x4 = *(const float4*)&x[tn * INP + j * KX + k];
            xa[k + 0] = x4.x; xa[k + 1] = x4.y;
            xa[k + 2] = x4.z; xa[k + 3] = x4.w;
        }

        float acc = (a0 + a1) + (a2 + a3);
        acc += __shfl_xor(acc, 1);
        acc += __shfl_xor(acc, 2);
        acc += __shfl_xor(acc, 4);
        if (j == 0) gate_lds[rl] = acc + brow;
        __syncthreads();

        if (tid < HSL) {
            const float iv = fast_sigmoid(gate_lds[tid]);
            const float fv = fast_sigmoid(gate_lds[16 + tid]);
            const float gv = fast_tanh(gate_lds[32 + tid]);
            const float ov = fast_sigmoid(gate_lds[48 + tid]);
            c = fv * c + iv * gv;
            const float hv = ov * fast_tanh(c);
            // publish packet (tag t+1, h) — single 8B atomic, self-ordering
            const u64 pkt = ((u64)(t + 1) << 32) | (u64)__float_as_uint(hv);
            __hip_atomic_store(&hbuf[((t + 1) & 1) * HID + w * HSL + tid], pkt,
                               __ATOMIC_RELAXED, __HIP_MEMORY_SCOPE_AGENT);
            // fused output projection partial — after publish
            float pd = hv * weff;
            pd += __shfl_xor(pd, 1);
            pd += __shfl_xor(pd, 2);
            pd += __shfl_xor(pd, 4);
            pd += __shfl_xor(pd, 8);
            if (tid == 0) atomicAdd(&out[t], pd);
        }
    }
}

// out[t] starts at b_eff = dot(b1, Wout); persistent kernel atomicAdds the
// h-projection partials on top.
__global__ void init_out(const float* __restrict__ b1,
                         const float* __restrict__ Wout,
                         float* __restrict__ out)
{
    const int t = blockIdx.x * blockDim.x + threadIdx.x;
    float be = 0.0f;
    for (int p = 0; p < 25; ++p) be += b1[p] * Wout[p];
    if (t < T_SEQ) out[t] = be;
}

extern "C" void kernel_launch(void* const* d_in, const int* in_sizes, int n_in,
                              void* d_out, int out_size, void* d_ws, size_t ws_size,
                              hipStream_t stream)
{
    const float* x    = (const float*)d_in[0];
    const float* W_ih = (const float*)d_in[1];
    const float* W_hh = (const float*)d_in[2];
    const float* b_ih = (const float*)d_in[3];
    const float* b_hh = (const float*)d_in[4];
    const float* W1   = (const float*)d_in[5];
    const float* b1   = (const float*)d_in[6];
    const float* Wout = (const float*)d_in[7];
    float* out = (float*)d_out;

    u64* hbuf = (u64*)d_ws;    // 2 x 512 packets = 8 KB

    // zero packets: tag 0 + h 0 == valid initial state for step 0
    hipMemsetAsync(d_ws, 0, 2 * HID * sizeof(u64), stream);
    init_out<<<(T_SEQ + 255) / 256, 256, 0, stream>>>(b1, Wout, out);
    lstm_persist<<<NWG, NTH, 0, stream>>>(x, W_ih, W_hh, b_ih, b_hh, W1, Wout,
                                          hbuf, out);
}